// Round 1
// baseline (268.196 us; speedup 1.0000x reference)
//
#include <hip/hip_runtime.h>

// Problem constants
// C=1024, RC=64, L=49 (7x7), LQ=64 (8x8), BZ=4, N=256, BP=1024

// ---- workspace layout (float offsets) ----
#define WQBAR  0         // [4][49] qbar (mean over s of q_feat), includes 1/64
#define WSUMQ  256       // [4] sum_l qbar[b][l]
#define WPCBW  320       // [1024] mean over r of pc_w rows (includes 1/64)
#define WPCBB  1344      // [1] mean of pc_b
#define WQF    1408      // [4][64][49] q_feat
#define WPMWT  14336     // [64][1024] pm_w transposed
#define WQMWT  79872     // [64][1024] qm_w transposed
#define WQATT  145408    // [1024][1024] q_att
#define WRQT   1193984   // [4][49][1024] resized query, transposed (l-major, c fastest)
// total ~1394688 floats (~5.6 MB)

// ---- output layout (float offsets) ----
#define OUT_FP 0          // f_props [1024][1024][49]
#define OUT_FQ 51380224   // f_query [1024][1024][64]
#define OUT_PA 118489088  // p_att   [1024][1024]

__device__ __forceinline__ float sigmoidf(float v) {
    return 1.0f / (1.0f + __expf(-v));
}

// K1a: bilinear 8x8 -> 7x7 (jax.image.resize, antialias=True), store transposed [b][l][c]
__global__ void k_resizeT(const float* __restrict__ xq, float* __restrict__ rqT) {
    int g = blockIdx.x * blockDim.x + threadIdx.x;  // < 4*49*1024 = 200704
    int b = g / 50176;
    int rem = g - b * 50176;
    int l = rem >> 10;
    int c = rem & 1023;
    int i = l / 7, j = l - i * 7;
    // antialiased triangle kernel, 2 taps, analytically derived weights
    float fi = (2 * i + 1) * (1.0f / 14.0f);
    float fj = (2 * j + 1) * (1.0f / 14.0f);
    float wi0 = (1.0f - 0.875f * fi) * (1.0f / 1.125f); float wi1 = 1.0f - wi0;
    float wj0 = (1.0f - 0.875f * fj) * (1.0f / 1.125f); float wj1 = 1.0f - wj0;
    const float* X = xq + ((size_t)(b * 1024 + c) << 6);
    float v = wi0 * (wj0 * X[i * 8 + j]       + wj1 * X[i * 8 + j + 1])
            + wi1 * (wj0 * X[(i + 1) * 8 + j] + wj1 * X[(i + 1) * 8 + j + 1]);
    rqT[g] = v;  // g == (b*49+l)*1024 + c
}

// K1b: q_feat[b][s][l] = qc_b[s] + sum_c qc_w[s][c] * rqT[b][l][c]; one wave per dot
__global__ void k_qfeat(const float* __restrict__ qc_w, const float* __restrict__ qc_b,
                        const float* __restrict__ rqT, float* __restrict__ qf) {
    int wave = threadIdx.x >> 6, lane = threadIdx.x & 63;
    int d = blockIdx.x * 4 + wave;  // < 12544
    int b = d / 3136;
    int rem = d - b * 3136;
    int s = rem / 49;
    int l = rem - s * 49;
    const float* wr = qc_w + s * 1024;
    const float* xr = rqT + (size_t)(b * 49 + l) * 1024;
    float part = 0.0f;
    #pragma unroll
    for (int k = 0; k < 16; ++k) part += wr[k * 64 + lane] * xr[k * 64 + lane];
    #pragma unroll
    for (int off = 32; off; off >>= 1) part += __shfl_down(part, off, 64);
    if (lane == 0) qf[d] = part + qc_b[s];
}

// K1c: qbar, sumqbar, pcbar_w, pcbar_b (single block, 1024 threads)
__global__ void k_stats(const float* __restrict__ pc_w, const float* __restrict__ pc_b,
                        const float* __restrict__ qf, float* __restrict__ ws) {
    __shared__ float qb_s[196];
    int t = threadIdx.x;
    if (t < 196) {
        int b = t / 49, l = t - b * 49;
        float s = 0.0f;
        for (int ss = 0; ss < 64; ++ss) s += qf[b * 3136 + ss * 49 + l];
        s *= (1.0f / 64.0f);
        qb_s[t] = s;
        ws[WQBAR + t] = s;
    }
    {
        float s = 0.0f;
        for (int r = 0; r < 64; ++r) s += pc_w[r * 1024 + t];
        ws[WPCBW + t] = s * (1.0f / 64.0f);
    }
    if (t == 0) {
        float s = 0.0f;
        for (int r = 0; r < 64; ++r) s += pc_b[r];
        ws[WPCBB] = s * (1.0f / 64.0f);
    }
    __syncthreads();
    if (t < 4) {
        float s = 0.0f;
        for (int l = 0; l < 49; ++l) s += qb_s[t * 49 + l];
        ws[WSUMQ + t] = s;
    }
}

// K1d: transpose pm_w, qm_w  [C][RC] -> [RC][C] for coalesced reads in k_prop
__global__ void k_transpose(const float* __restrict__ pm_w, const float* __restrict__ qm_w,
                            float* __restrict__ ws) {
    int idx = blockIdx.x * 256 + threadIdx.x;  // < 131072
    int r = (idx & 65535) >> 10, c = idx & 1023;
    if (idx < 65536) ws[WPMWT + idx] = pm_w[c * 64 + r];
    else             ws[WQMWT + (idx - 65536)] = qm_w[c * 64 + r];
}

// K2: per-prop — y & pbar reductions over x, then p_rel/q_rel, then sigmoid MLPs
__global__ __launch_bounds__(256) void k_prop(
    const float* __restrict__ x,
    const float* __restrict__ pc_w, const float* __restrict__ pc_b,
    const float* __restrict__ pm_b, const float* __restrict__ qm_b,
    float* __restrict__ ws, float* __restrict__ patt_out)
{
    __shared__ float xs[64][51];   // pad 51: gcd(51,32)=1 -> conflict-free column reads
    __shared__ float y_s[1024];
    __shared__ float pcb_s[1024];
    __shared__ float qbar_s[64];
    __shared__ float pbar_s[49];
    __shared__ float prel_s[64];
    __shared__ float qrel_s[64];

    const int t = threadIdx.x, wave = t >> 6, lane = t & 63;
    const int p = blockIdx.x, b = p >> 8;

    if (t < 49) qbar_s[t] = ws[WQBAR + b * 49 + t];
    for (int k = t; k < 1024; k += 256) pcb_s[k] = ws[WPCBW + k];
    const float sumqbar = ws[WSUMQ + b];
    const float pcbarb  = ws[WPCBB];
    __syncthreads();

    const float* xp = x + (size_t)p * (1024 * 49);
    float pbar_acc = 0.0f;

    for (int g = 0; g < 16; ++g) {
        const float4* src4 = (const float4*)(xp + g * (64 * 49));
        for (int k = t; k < 784; k += 256) {
            float4 v = src4[k];
            int e = k * 4;
            float vals[4] = {v.x, v.y, v.z, v.w};
            #pragma unroll
            for (int j = 0; j < 4; ++j) {
                int ee = e + j;
                int cc = ee / 49;
                xs[cc][ee - cc * 49] = vals[j];
            }
        }
        __syncthreads();
        if (wave == 0) {
            float acc = 0.0f;
            #pragma unroll
            for (int l = 0; l < 49; ++l) acc += xs[lane][l] * qbar_s[l];
            y_s[g * 64 + lane] = acc;
        } else if (wave == 1 && lane < 49) {
            float a = 0.0f;
            #pragma unroll
            for (int c = 0; c < 64; ++c) a += pcb_s[g * 64 + c] * xs[c][lane];
            pbar_acc += a;
        }
        __syncthreads();
    }
    if (wave == 1 && lane < 49) pbar_s[lane] = pbar_acc + pcbarb;
    __syncthreads();

    // p_rel[r] = pc_w[r,:] . y + pc_b[r]*sumqbar ; wave w handles rows w*16..w*16+15
    for (int i = 0; i < 16; ++i) {
        int r = wave * 16 + i;
        const float* wr = pc_w + r * 1024;
        float part = 0.0f;
        #pragma unroll
        for (int k = 0; k < 16; ++k) part += wr[k * 64 + lane] * y_s[k * 64 + lane];
        #pragma unroll
        for (int off = 32; off; off >>= 1) part += __shfl_down(part, off, 64);
        if (lane == 0) prel_s[r] = part + pc_b[r] * sumqbar;
    }
    __syncthreads();
    if (t < 64) {
        const float* qfr = ws + WQF + (b * 3136 + t * 49);
        float a = 0.0f;
        #pragma unroll
        for (int l = 0; l < 49; ++l) a += pbar_s[l] * qfr[l];
        qrel_s[t] = a;
    }
    __syncthreads();

    // attention MLPs: att[c] = sigmoid(sum_r wT[r][c]*rel[r] + b[c]); coalesced float4
    const float4* pmT4 = (const float4*)(ws + WPMWT);
    const float4* qmT4 = (const float4*)(ws + WQMWT);
    float4 pa = {0, 0, 0, 0}, qa = {0, 0, 0, 0};
    for (int r = 0; r < 64; ++r) {
        float4 wp = pmT4[r * 256 + t];
        float4 wq = qmT4[r * 256 + t];
        float pr = prel_s[r], qr = qrel_s[r];
        pa.x += wp.x * pr; pa.y += wp.y * pr; pa.z += wp.z * pr; pa.w += wp.w * pr;
        qa.x += wq.x * qr; qa.y += wq.y * qr; qa.z += wq.z * qr; qa.w += wq.w * qr;
    }
    float4 pb = ((const float4*)pm_b)[t];
    float4 qb = ((const float4*)qm_b)[t];
    float4 po, qo;
    po.x = sigmoidf(pa.x + pb.x); po.y = sigmoidf(pa.y + pb.y);
    po.z = sigmoidf(pa.z + pb.z); po.w = sigmoidf(pa.w + pb.w);
    qo.x = sigmoidf(qa.x + qb.x); qo.y = sigmoidf(qa.y + qb.y);
    qo.z = sigmoidf(qa.z + qb.z); qo.w = sigmoidf(qa.w + qb.w);
    ((float4*)patt_out)[p * 256 + t] = po;
    ((float4*)(ws + WQATT))[p * 256 + t] = qo;
}

// K3: f_props = x_props * p_att (broadcast over 49 spatial)
__global__ void k_fprops(const float* __restrict__ x, const float* __restrict__ patt,
                         float* __restrict__ out) {
    const unsigned total4 = 51380224u / 4u;
    unsigned stride = gridDim.x * blockDim.x;
    for (unsigned i = blockIdx.x * blockDim.x + threadIdx.x; i < total4; i += stride) {
        float4 v = ((const float4*)x)[i];
        unsigned e = i * 4u;
        v.x *= patt[e / 49u];
        v.y *= patt[(e + 1u) / 49u];
        v.z *= patt[(e + 2u) / 49u];
        v.w *= patt[(e + 3u) / 49u];
        ((float4*)out)[i] = v;
    }
}

// K4: f_query = broadcast(x_query) * q_att
__global__ void k_fquery(const float* __restrict__ xq, const float* __restrict__ qatt,
                         float* __restrict__ out) {
    const unsigned total4 = 67108864u / 4u;  // 16777216
    unsigned stride = gridDim.x * blockDim.x;
    for (unsigned i = blockIdx.x * blockDim.x + threadIdx.x; i < total4; i += stride) {
        float att = qatt[i >> 4];
        unsigned b = i >> 22;
        float4 v = ((const float4*)xq)[(b << 14) | (i & 16383u)];
        v.x *= att; v.y *= att; v.z *= att; v.w *= att;
        ((float4*)out)[i] = v;
    }
}

extern "C" void kernel_launch(void* const* d_in, const int* in_sizes, int n_in,
                              void* d_out, int out_size, void* d_ws, size_t ws_size,
                              hipStream_t stream) {
    const float* x_props = (const float*)d_in[0];
    const float* x_query = (const float*)d_in[1];
    const float* pc_w    = (const float*)d_in[2];
    const float* pc_b    = (const float*)d_in[3];
    const float* qc_w    = (const float*)d_in[4];
    const float* qc_b    = (const float*)d_in[5];
    const float* pm_w    = (const float*)d_in[6];
    const float* pm_b    = (const float*)d_in[7];
    const float* qm_w    = (const float*)d_in[8];
    const float* qm_b    = (const float*)d_in[9];
    float* out = (float*)d_out;
    float* ws  = (float*)d_ws;

    k_resizeT<<<784, 256, 0, stream>>>(x_query, ws + WRQT);
    k_qfeat<<<3136, 256, 0, stream>>>(qc_w, qc_b, ws + WRQT, ws + WQF);
    k_stats<<<1, 1024, 0, stream>>>(pc_w, pc_b, ws + WQF, ws);
    k_transpose<<<512, 256, 0, stream>>>(pm_w, qm_w, ws);
    k_prop<<<1024, 256, 0, stream>>>(x_props, pc_w, pc_b, pm_b, qm_b, ws, out + OUT_PA);
    k_fprops<<<4096, 256, 0, stream>>>(x_props, out + OUT_PA, out + OUT_FP);
    k_fquery<<<4096, 256, 0, stream>>>(x_query, ws + WQATT, out + OUT_FQ);
}

// Round 2
// 241.410 us; speedup vs baseline: 1.1110x; 1.1110x over previous
//
#include <hip/hip_runtime.h>

// Problem constants: C=1024, RC=64, L=49 (7x7), LQ=64 (8x8), BZ=4, N=256, BP=1024

// ---- workspace layout (float offsets) ----
#define WQBAR  0         // [4][49] qbar (mean over s of q_feat), includes 1/64
#define WSUMQ  256       // [4] sum_l qbar[b][l]
#define WPCBW  320       // [1024] mean over r of pc_w rows (includes 1/64)
#define WPCBB  1344      // [1] mean of pc_b
#define WQF    1408      // [4][64][49] q_feat
#define WPMWT  14336     // [64][1024] pm_w transposed
#define WQMWT  79872     // [64][1024] qm_w transposed
#define WRQT   145408    // [4][49][1024] resized query, transposed (l-major, c fastest)

// ---- output layout (float offsets) ----
#define OUT_FP 0          // f_props [1024][1024][49]
#define OUT_FQ 51380224   // f_query [1024][1024][64]
#define OUT_PA 118489088  // p_att   [1024][1024]

__device__ __forceinline__ float sigmoidf(float v) {
    return 1.0f / (1.0f + __expf(-v));
}

// K1: bilinear 8x8 -> 7x7 (jax.image.resize, antialias=True), store transposed [b][l][c]
__global__ void k_resizeT(const float* __restrict__ xq, float* __restrict__ rqT) {
    int g = blockIdx.x * blockDim.x + threadIdx.x;  // < 4*49*1024 = 200704
    int b = g / 50176;
    int rem = g - b * 50176;
    int l = rem >> 10;
    int c = rem & 1023;
    int i = l / 7, j = l - i * 7;
    float fi = (2 * i + 1) * (1.0f / 14.0f);
    float fj = (2 * j + 1) * (1.0f / 14.0f);
    float wi0 = (1.0f - 0.875f * fi) * (1.0f / 1.125f); float wi1 = 1.0f - wi0;
    float wj0 = (1.0f - 0.875f * fj) * (1.0f / 1.125f); float wj1 = 1.0f - wj0;
    const float* X = xq + ((size_t)(b * 1024 + c) << 6);
    float v = wi0 * (wj0 * X[i * 8 + j]       + wj1 * X[i * 8 + j + 1])
            + wi1 * (wj0 * X[(i + 1) * 8 + j] + wj1 * X[(i + 1) * 8 + j + 1]);
    rqT[g] = v;  // g == (b*49+l)*1024 + c
}

// K2: q_feat[b][s][l] = qc_b[s] + sum_c qc_w[s][c] * rqT[b][l][c]; one wave per dot
__global__ void k_qfeat(const float* __restrict__ qc_w, const float* __restrict__ qc_b,
                        const float* __restrict__ rqT, float* __restrict__ qf) {
    int wave = threadIdx.x >> 6, lane = threadIdx.x & 63;
    int d = blockIdx.x * 4 + wave;  // < 12544
    int b = d / 3136;
    int rem = d - b * 3136;
    int s = rem / 49;
    int l = rem - s * 49;
    const float* wr = qc_w + s * 1024;
    const float* xr = rqT + (size_t)(b * 49 + l) * 1024;
    float part = 0.0f;
    #pragma unroll
    for (int k = 0; k < 16; ++k) part += wr[k * 64 + lane] * xr[k * 64 + lane];
    #pragma unroll
    for (int off = 32; off; off >>= 1) part += __shfl_down(part, off, 64);
    if (lane == 0) qf[d] = part + qc_b[s];
}

// K3: block 0 = stats (qbar/sumq/pc-row-means); blocks 1..128 = transpose pm_w,qm_w
__global__ __launch_bounds__(1024) void k_prep(
    const float* __restrict__ pc_w, const float* __restrict__ pc_b,
    const float* __restrict__ qf,
    const float* __restrict__ pm_w, const float* __restrict__ qm_w,
    float* __restrict__ ws)
{
    int t = threadIdx.x;
    if (blockIdx.x == 0) {
        __shared__ float qb_s[196];
        if (t < 196) {
            int b = t / 49, l = t - b * 49;
            float s = 0.0f;
            for (int ss = 0; ss < 64; ++ss) s += qf[b * 3136 + ss * 49 + l];
            s *= (1.0f / 64.0f);
            qb_s[t] = s;
            ws[WQBAR + t] = s;
        }
        {
            float s = 0.0f;
            for (int r = 0; r < 64; ++r) s += pc_w[r * 1024 + t];
            ws[WPCBW + t] = s * (1.0f / 64.0f);
        }
        if (t == 0) {
            float s = 0.0f;
            for (int r = 0; r < 64; ++r) s += pc_b[r];
            ws[WPCBB] = s * (1.0f / 64.0f);
        }
        __syncthreads();
        if (t < 4) {
            float s = 0.0f;
            for (int l = 0; l < 49; ++l) s += qb_s[t * 49 + l];
            ws[WSUMQ + t] = s;
        }
    } else {
        int idx = (blockIdx.x - 1) * 1024 + t;  // < 131072
        int r = (idx & 65535) >> 10, c = idx & 1023;
        if (idx < 65536) ws[WPMWT + idx] = pm_w[c * 64 + r];
        else             ws[WQMWT + (idx - 65536)] = qm_w[c * 64 + r];
    }
}

// K4: per-prop fused — reductions over x -> p_rel/q_rel -> sigmoid MLPs ->
//     p_att out + f_props + f_query streaming writes (x re-read is L2/L3-hot)
__global__ __launch_bounds__(256) void k_prop(
    const float* __restrict__ x, const float* __restrict__ xq,
    const float* __restrict__ pc_w, const float* __restrict__ pc_b,
    const float* __restrict__ pm_b, const float* __restrict__ qm_b,
    const float* __restrict__ ws,
    float* __restrict__ fprops, float* __restrict__ fquery, float* __restrict__ patt_out)
{
    __shared__ float xs[64][51];   // pad 51: gcd(51,32)=1 -> conflict-free column reads
    __shared__ float y_s[1024];    // reused as p_att after MLP
    __shared__ float pcb_s[1024];  // reused as q_att after MLP
    __shared__ float qbar_s[64];
    __shared__ float pbar_s[49];
    __shared__ float prel_s[64];
    __shared__ float qrel_s[64];

    const int t = threadIdx.x, wave = t >> 6, lane = t & 63;
    const int p = blockIdx.x, b = p >> 8;

    if (t < 49) qbar_s[t] = ws[WQBAR + b * 49 + t];
    for (int k = t; k < 1024; k += 256) pcb_s[k] = ws[WPCBW + k];
    const float sumqbar = ws[WSUMQ + b];
    const float pcbarb  = ws[WPCBB];
    __syncthreads();

    const float* xp = x + (size_t)p * (1024 * 49);
    float pbar_acc = 0.0f;

    for (int g = 0; g < 16; ++g) {
        const float4* src4 = (const float4*)(xp + g * (64 * 49));
        for (int k = t; k < 784; k += 256) {
            float4 v = src4[k];
            int e = k * 4;
            float vals[4] = {v.x, v.y, v.z, v.w};
            #pragma unroll
            for (int j = 0; j < 4; ++j) {
                int ee = e + j;
                int cc = ee / 49;
                xs[cc][ee - cc * 49] = vals[j];
            }
        }
        __syncthreads();
        if (wave == 0) {
            float acc = 0.0f;
            #pragma unroll
            for (int l = 0; l < 49; ++l) acc += xs[lane][l] * qbar_s[l];
            y_s[g * 64 + lane] = acc;
        } else if (wave == 1 && lane < 49) {
            float a = 0.0f;
            #pragma unroll
            for (int c = 0; c < 64; ++c) a += pcb_s[g * 64 + c] * xs[c][lane];
            pbar_acc += a;
        }
        __syncthreads();
    }
    if (wave == 1 && lane < 49) pbar_s[lane] = pbar_acc + pcbarb;
    __syncthreads();

    // p_rel[r] = pc_w[r,:] . y + pc_b[r]*sumqbar ; wave w handles rows w*16..w*16+15
    for (int i = 0; i < 16; ++i) {
        int r = wave * 16 + i;
        const float* wr = pc_w + r * 1024;
        float part = 0.0f;
        #pragma unroll
        for (int k = 0; k < 16; ++k) part += wr[k * 64 + lane] * y_s[k * 64 + lane];
        #pragma unroll
        for (int off = 32; off; off >>= 1) part += __shfl_down(part, off, 64);
        if (lane == 0) prel_s[r] = part + pc_b[r] * sumqbar;
    }
    __syncthreads();
    if (t < 64) {
        const float* qfr = ws + WQF + (b * 3136 + t * 49);
        float a = 0.0f;
        #pragma unroll
        for (int l = 0; l < 49; ++l) a += pbar_s[l] * qfr[l];
        qrel_s[t] = a;
    }
    __syncthreads();

    // attention MLPs: att[c] = sigmoid(sum_r wT[r][c]*rel[r] + b[c]); coalesced float4
    const float4* pmT4 = (const float4*)(ws + WPMWT);
    const float4* qmT4 = (const float4*)(ws + WQMWT);
    float4 pa = {0, 0, 0, 0}, qa = {0, 0, 0, 0};
    for (int r = 0; r < 64; ++r) {
        float4 wp = pmT4[r * 256 + t];
        float4 wq = qmT4[r * 256 + t];
        float pr = prel_s[r], qr = qrel_s[r];
        pa.x += wp.x * pr; pa.y += wp.y * pr; pa.z += wp.z * pr; pa.w += wp.w * pr;
        qa.x += wq.x * qr; qa.y += wq.y * qr; qa.z += wq.z * qr; qa.w += wq.w * qr;
    }
    float4 pb = ((const float4*)pm_b)[t];
    float4 qb = ((const float4*)qm_b)[t];
    float4 po, qo;
    po.x = sigmoidf(pa.x + pb.x); po.y = sigmoidf(pa.y + pb.y);
    po.z = sigmoidf(pa.z + pb.z); po.w = sigmoidf(pa.w + pb.w);
    qo.x = sigmoidf(qa.x + qb.x); qo.y = sigmoidf(qa.y + qb.y);
    qo.z = sigmoidf(qa.z + qb.z); qo.w = sigmoidf(qa.w + qb.w);
    ((float4*)patt_out)[p * 256 + t] = po;

    // stash attentions in LDS (y_s/pcb_s are dead now)
    ((float4*)y_s)[t]   = po;   // p_att
    ((float4*)pcb_s)[t] = qo;   // q_att
    __syncthreads();

    // f_props = x * p_att  (x re-read is L2/L3-resident: this block just streamed it)
    const float4* xp4 = (const float4*)xp;
    float4* fp4 = (float4*)(fprops + (size_t)p * 50176);
    for (int k = t; k < 12544; k += 256) {
        float4 v = xp4[k];
        unsigned e = (unsigned)k * 4u;
        v.x *= y_s[e / 49u];
        v.y *= y_s[(e + 1u) / 49u];
        v.z *= y_s[(e + 2u) / 49u];
        v.w *= y_s[(e + 3u) / 49u];
        fp4[k] = v;
    }
    // f_query = x_query[b] * q_att  (x_query is 16 MB total, cache-resident)
    const float4* xq4 = (const float4*)(xq + (size_t)b * 65536);
    float4* fq4 = (float4*)(fquery + (size_t)p * 65536);
    for (int k = t; k < 16384; k += 256) {
        float att = pcb_s[k >> 4];
        float4 v = xq4[k];
        v.x *= att; v.y *= att; v.z *= att; v.w *= att;
        fq4[k] = v;
    }
}

extern "C" void kernel_launch(void* const* d_in, const int* in_sizes, int n_in,
                              void* d_out, int out_size, void* d_ws, size_t ws_size,
                              hipStream_t stream) {
    const float* x_props = (const float*)d_in[0];
    const float* x_query = (const float*)d_in[1];
    const float* pc_w    = (const float*)d_in[2];
    const float* pc_b    = (const float*)d_in[3];
    const float* qc_w    = (const float*)d_in[4];
    const float* qc_b    = (const float*)d_in[5];
    const float* pm_w    = (const float*)d_in[6];
    const float* pm_b    = (const float*)d_in[7];
    const float* qm_w    = (const float*)d_in[8];
    const float* qm_b    = (const float*)d_in[9];
    float* out = (float*)d_out;
    float* ws  = (float*)d_ws;

    k_resizeT<<<784, 256, 0, stream>>>(x_query, ws + WRQT);
    k_qfeat<<<3136, 256, 0, stream>>>(qc_w, qc_b, ws + WRQT, ws + WQF);
    k_prep<<<129, 1024, 0, stream>>>(pc_w, pc_b, ws + WQF, pm_w, qm_w, ws);
    k_prop<<<1024, 256, 0, stream>>>(x_props, x_query, pc_w, pc_b, pm_b, qm_b, ws,
                                     out + OUT_FP, out + OUT_FQ, out + OUT_PA);
}

// Round 3
// 237.562 us; speedup vs baseline: 1.1290x; 1.0162x over previous
//
#include <hip/hip_runtime.h>

// Problem constants: C=1024, RC=64, L=49 (7x7), LQ=64 (8x8), BZ=4, N=256, BP=1024

// ---- workspace layout (float offsets) ----
#define WQBAR  0         // [4][49] qbar (mean over s of q_feat), includes 1/64
#define WSUMQ  256       // [4] sum_l qbar[b][l]
#define WPCBW  320       // [1024] mean over r of pc_w rows (includes 1/64)
#define WPCBB  1344      // [1] mean of pc_b
#define WQF    1408      // [4][64][49] q_feat
#define WPMWT  14336     // [64][1024] pm_w transposed
#define WQMWT  79872     // [64][1024] qm_w transposed
#define WRQT   145408    // [4][49][1024] resized query, transposed (l-major, c fastest)

// ---- output layout (float offsets) ----
#define OUT_FP 0          // f_props [1024][1024][49]
#define OUT_FQ 51380224   // f_query [1024][1024][64]
#define OUT_PA 118489088  // p_att   [1024][1024]

__device__ __forceinline__ float sigmoidf(float v) {
    return 1.0f / (1.0f + __expf(-v));
}

// K1: bilinear 8x8 -> 7x7 (jax.image.resize, antialias=True), store transposed [b][l][c]
__global__ void k_resizeT(const float* __restrict__ xq, float* __restrict__ rqT) {
    int g = blockIdx.x * blockDim.x + threadIdx.x;  // < 4*49*1024 = 200704
    int b = g / 50176;
    int rem = g - b * 50176;
    int l = rem >> 10;
    int c = rem & 1023;
    int i = l / 7, j = l - i * 7;
    float fi = (2 * i + 1) * (1.0f / 14.0f);
    float fj = (2 * j + 1) * (1.0f / 14.0f);
    float wi0 = (1.0f - 0.875f * fi) * (1.0f / 1.125f); float wi1 = 1.0f - wi0;
    float wj0 = (1.0f - 0.875f * fj) * (1.0f / 1.125f); float wj1 = 1.0f - wj0;
    const float* X = xq + ((size_t)(b * 1024 + c) << 6);
    float v = wi0 * (wj0 * X[i * 8 + j]       + wj1 * X[i * 8 + j + 1])
            + wi1 * (wj0 * X[(i + 1) * 8 + j] + wj1 * X[(i + 1) * 8 + j + 1]);
    rqT[g] = v;  // g == (b*49+l)*1024 + c
}

// K2: q_feat[b][s][l] = qc_b[s] + sum_c qc_w[s][c] * rqT[b][l][c]; one wave per dot
__global__ void k_qfeat(const float* __restrict__ qc_w, const float* __restrict__ qc_b,
                        const float* __restrict__ rqT, float* __restrict__ qf) {
    int wave = threadIdx.x >> 6, lane = threadIdx.x & 63;
    int d = blockIdx.x * 4 + wave;  // < 12544
    int b = d / 3136;
    int rem = d - b * 3136;
    int s = rem / 49;
    int l = rem - s * 49;
    const float* wr = qc_w + s * 1024;
    const float* xr = rqT + (size_t)(b * 49 + l) * 1024;
    float part = 0.0f;
    #pragma unroll
    for (int k = 0; k < 16; ++k) part += wr[k * 64 + lane] * xr[k * 64 + lane];
    #pragma unroll
    for (int off = 32; off; off >>= 1) part += __shfl_down(part, off, 64);
    if (lane == 0) qf[d] = part + qc_b[s];
}

// K3: block 0 = stats (qbar/sumq/pc-row-means); blocks 1..128 = transpose pm_w,qm_w
__global__ __launch_bounds__(1024) void k_prep(
    const float* __restrict__ pc_w, const float* __restrict__ pc_b,
    const float* __restrict__ qf,
    const float* __restrict__ pm_w, const float* __restrict__ qm_w,
    float* __restrict__ ws)
{
    int t = threadIdx.x;
    if (blockIdx.x == 0) {
        __shared__ float qb_s[196];
        if (t < 196) {
            int b = t / 49, l = t - b * 49;
            float s = 0.0f;
            for (int ss = 0; ss < 64; ++ss) s += qf[b * 3136 + ss * 49 + l];
            s *= (1.0f / 64.0f);
            qb_s[t] = s;
            ws[WQBAR + t] = s;
        }
        {
            float s = 0.0f;
            for (int r = 0; r < 64; ++r) s += pc_w[r * 1024 + t];
            ws[WPCBW + t] = s * (1.0f / 64.0f);
        }
        if (t == 0) {
            float s = 0.0f;
            for (int r = 0; r < 64; ++r) s += pc_b[r];
            ws[WPCBB] = s * (1.0f / 64.0f);
        }
        __syncthreads();
        if (t < 4) {
            float s = 0.0f;
            for (int l = 0; l < 49; ++l) s += qb_s[t * 49 + l];
            ws[WSUMQ + t] = s;
        }
    } else {
        int idx = (blockIdx.x - 1) * 1024 + t;  // < 131072
        int r = (idx & 65535) >> 10, c = idx & 1023;
        if (idx < 65536) ws[WPMWT + idx] = pm_w[c * 64 + r];
        else             ws[WQMWT + (idx - 65536)] = qm_w[c * 64 + r];
    }
}

// K4: per-prop fused. Linear LDS tile [256][49]: stride 49 is odd -> both the
// per-row (stride-49 across lanes) and per-column (stride-1) read patterns are
// bank-conflict-free (2 lanes/bank max = free). 512 threads, 4 chunks, all
// waves active; division-free attention indexing in the write phase.
__global__ __launch_bounds__(512) void k_prop(
    const float* __restrict__ x, const float* __restrict__ xq,
    const float* __restrict__ pc_w, const float* __restrict__ pc_b,
    const float* __restrict__ pm_b, const float* __restrict__ qm_b,
    const float* __restrict__ ws,
    float* __restrict__ fprops, float* __restrict__ fquery, float* __restrict__ patt_out)
{
    __shared__ float xs[12544];       // [256][49] one channel-chunk
    __shared__ float y_s[1024];       // y; reused as p_att
    __shared__ float pcb_s[1024];     // pc-row-means; reused as q_att
    __shared__ float qbar_s[49];
    __shared__ float pbar_part[4][49];
    __shared__ float pbar_s[49];
    __shared__ float prel_s[64];
    __shared__ float qrel_s[64];

    const int t = threadIdx.x, wave = t >> 6, lane = t & 63;
    const int p = blockIdx.x, b = p >> 8;

    if (t < 49) qbar_s[t] = ws[WQBAR + b * 49 + t];
    for (int k = t; k < 1024; k += 512) pcb_s[k] = ws[WPCBW + k];
    const float sumqbar = ws[WSUMQ + b];
    const float pcbarb  = ws[WPCBB];

    const float* xp = x + (size_t)p * 50176;
    const float4* xp4 = (const float4*)xp;
    float pbar_acc = 0.0f;

    for (int ch = 0; ch < 4; ++ch) {
        __syncthreads();                       // xs free of prev readers (also covers pcb/qbar init)
        const float4* src = xp4 + ch * 3136;
        float4* xs4 = (float4*)xs;
        for (int k = t; k < 3136; k += 512) xs4[k] = src[k];
        __syncthreads();
        if (wave < 4) {
            int c = wave * 64 + lane;
            const float* row = xs + c * 49;
            float acc = 0.0f;
            #pragma unroll
            for (int l = 0; l < 49; ++l) acc += row[l] * qbar_s[l];
            y_s[ch * 256 + c] = acc;
        } else if (lane < 49) {
            int cw = (wave - 4) * 64;
            const float* base = xs + cw * 49 + lane;
            const float* pw = pcb_s + ch * 256 + cw;
            float a = 0.0f;
            #pragma unroll
            for (int c = 0; c < 64; ++c) a += pw[c] * base[c * 49];
            pbar_acc += a;
        }
    }
    if (wave >= 4 && lane < 49) pbar_part[wave - 4][lane] = pbar_acc;
    __syncthreads();
    if (t < 49)
        pbar_s[t] = pbar_part[0][t] + pbar_part[1][t] + pbar_part[2][t] + pbar_part[3][t] + pcbarb;
    __syncthreads();

    // p_rel[r] = pc_w[r,:].y + pc_b[r]*sumqbar ; 8 waves x 8 rows
    #pragma unroll
    for (int i = 0; i < 8; ++i) {
        int r = wave * 8 + i;
        const float* wr = pc_w + r * 1024;
        float part = 0.0f;
        #pragma unroll
        for (int k = 0; k < 16; ++k) part += wr[k * 64 + lane] * y_s[k * 64 + lane];
        #pragma unroll
        for (int off = 32; off; off >>= 1) part += __shfl_down(part, off, 64);
        if (lane == 0) prel_s[r] = part + pc_b[r] * sumqbar;
    }
    if (t < 64) {
        const float* qfr = ws + WQF + (b * 3136 + t * 49);
        float a = 0.0f;
        #pragma unroll
        for (int l = 0; l < 49; ++l) a += pbar_s[l] * qfr[l];
        qrel_s[t] = a;
    }
    __syncthreads();

    // MLPs: threads 0-255 -> p_att, 256-511 -> q_att (wave-uniform split)
    {
        int col = t & 255;
        const float4* wT4 = (const float4*)(ws + (t < 256 ? WPMWT : WQMWT));
        const float* rel  = (t < 256) ? prel_s : qrel_s;
        float4 acc = {0, 0, 0, 0};
        for (int r = 0; r < 64; ++r) {
            float4 w4 = wT4[r * 256 + col];
            float rv = rel[r];
            acc.x += w4.x * rv; acc.y += w4.y * rv; acc.z += w4.z * rv; acc.w += w4.w * rv;
        }
        const float4* bias4 = (const float4*)((t < 256) ? pm_b : qm_b);
        float4 bb = bias4[col];
        float4 o;
        o.x = sigmoidf(acc.x + bb.x); o.y = sigmoidf(acc.y + bb.y);
        o.z = sigmoidf(acc.z + bb.z); o.w = sigmoidf(acc.w + bb.w);
        if (t < 256) {
            ((float4*)patt_out)[p * 256 + col] = o;
            ((float4*)y_s)[col] = o;           // p_att
        } else {
            ((float4*)pcb_s)[col] = o;         // q_att
        }
    }
    __syncthreads();

    // f_props = x * p_att, division-free: k = 49q + m tracked incrementally
    {
        float4* fp4 = (float4*)(fprops + (size_t)p * 50176);
        int q = t / 49;
        int m = t - q * 49;
        for (int k = t; k < 12544; k += 512) {
            float4 v = xp4[k];
            int i0 = 4 * m;
            int c0 = 4 * q + (i0 >= 49) + (i0 >= 98) + (i0 >= 147);
            int c1 = 4 * q + (i0 + 1 >= 49) + (i0 + 1 >= 98) + (i0 + 1 >= 147);
            int c2 = 4 * q + (i0 + 2 >= 49) + (i0 + 2 >= 98) + (i0 + 2 >= 147);
            int c3 = 4 * q + (i0 + 3 >= 49) + (i0 + 3 >= 98) + (i0 + 3 >= 147);
            v.x *= y_s[c0]; v.y *= y_s[c1]; v.z *= y_s[c2]; v.w *= y_s[c3];
            fp4[k] = v;
            q += 10; m += 22;                  // 512 = 49*10 + 22
            if (m >= 49) { m -= 49; ++q; }
        }
    }
    // f_query = x_query[b] * q_att
    {
        const float4* xq4 = (const float4*)(xq + (size_t)b * 65536);
        float4* fq4 = (float4*)(fquery + (size_t)p * 65536);
        for (int k = t; k < 16384; k += 512) {
            float att = pcb_s[k >> 4];
            float4 v = xq4[k];
            v.x *= att; v.y *= att; v.z *= att; v.w *= att;
            fq4[k] = v;
        }
    }
}

extern "C" void kernel_launch(void* const* d_in, const int* in_sizes, int n_in,
                              void* d_out, int out_size, void* d_ws, size_t ws_size,
                              hipStream_t stream) {
    const float* x_props = (const float*)d_in[0];
    const float* x_query = (const float*)d_in[1];
    const float* pc_w    = (const float*)d_in[2];
    const float* pc_b    = (const float*)d_in[3];
    const float* qc_w    = (const float*)d_in[4];
    const float* qc_b    = (const float*)d_in[5];
    const float* pm_w    = (const float*)d_in[6];
    const float* pm_b    = (const float*)d_in[7];
    const float* qm_w    = (const float*)d_in[8];
    const float* qm_b    = (const float*)d_in[9];
    float* out = (float*)d_out;
    float* ws  = (float*)d_ws;

    k_resizeT<<<784, 256, 0, stream>>>(x_query, ws + WRQT);
    k_qfeat<<<3136, 256, 0, stream>>>(qc_w, qc_b, ws + WRQT, ws + WQF);
    k_prep<<<129, 1024, 0, stream>>>(pc_w, pc_b, ws + WQF, pm_w, qm_w, ws);
    k_prop<<<1024, 512, 0, stream>>>(x_props, x_query, pc_w, pc_b, pm_b, qm_b, ws,
                                     out + OUT_FP, out + OUT_FQ, out + OUT_PA);
}

// Round 4
// 197.107 us; speedup vs baseline: 1.3607x; 1.2052x over previous
//
#include <hip/hip_runtime.h>

// Problem constants: C=1024, RC=64, L=49 (7x7), LQ=64 (8x8), BZ=4, N=256, BP=1024

// ---- workspace layout (float offsets) ----
#define WQBAR  0         // [4][49] qbar (mean over s of q_feat), includes 1/64
#define WSUMQ  256       // [4] sum_l qbar[b][l]
#define WPCBW  320       // [1024] mean over r of pc_w rows (includes 1/64)
#define WPCBB  1344      // [1] mean of pc_b
#define WQF    1408      // [4][64][49] q_feat
#define WPMBF  14336     // bf16 [64][1024] pm_w transposed (as 32768 floats)
#define WQMBF  47104     // bf16 [64][1024] qm_w transposed

// ---- output layout (float offsets) ----
#define OUT_FP 0          // f_props [1024][1024][49]
#define OUT_FQ 51380224   // f_query [1024][1024][64]
#define OUT_PA 118489088  // p_att   [1024][1024]

__device__ __forceinline__ float sigmoidf(float v) {
    return 1.0f / (1.0f + __expf(-v));
}
__device__ __forceinline__ unsigned short bf16_rne(float x) {
    unsigned u = __float_as_uint(x);
    return (unsigned short)((u + 0x7FFFu + ((u >> 16) & 1u)) >> 16);
}

// K1: per (b,l): bilinear resize column -> LDS, q_feat[b][:][l] (64 dots), qbar[b][l]
__global__ __launch_bounds__(1024) void k_qprep(
    const float* __restrict__ xq, const float* __restrict__ qc_w,
    const float* __restrict__ qc_b, float* __restrict__ ws)
{
    __shared__ float rq[1024];
    __shared__ float qf_s[64];
    const int blk = blockIdx.x;         // < 196
    const int b = blk / 49, l = blk - b * 49;
    const int t = threadIdx.x, wave = t >> 6, lane = t & 63;
    const int i = l / 7, j = l - i * 7;
    // antialiased bilinear (scale 7/8), analytic 2-tap weights
    float fi = (2 * i + 1) * (1.0f / 14.0f);
    float fj = (2 * j + 1) * (1.0f / 14.0f);
    float wi0 = (1.0f - 0.875f * fi) * (1.0f / 1.125f); float wi1 = 1.0f - wi0;
    float wj0 = (1.0f - 0.875f * fj) * (1.0f / 1.125f); float wj1 = 1.0f - wj0;
    const float* X = xq + ((size_t)(b * 1024 + t) << 6);
    rq[t] = wi0 * (wj0 * X[i * 8 + j]       + wj1 * X[i * 8 + j + 1])
          + wi1 * (wj0 * X[(i + 1) * 8 + j] + wj1 * X[(i + 1) * 8 + j + 1]);
    __syncthreads();
    #pragma unroll
    for (int ii = 0; ii < 4; ++ii) {
        int s = wave * 4 + ii;
        const float* wr = qc_w + s * 1024;
        float part = 0.0f;
        #pragma unroll
        for (int k = 0; k < 16; ++k) part += wr[k * 64 + lane] * rq[k * 64 + lane];
        #pragma unroll
        for (int off = 32; off; off >>= 1) part += __shfl_down(part, off, 64);
        if (lane == 0) {
            float val = part + qc_b[s];
            ws[WQF + b * 3136 + s * 49 + l] = val;
            qf_s[s] = val;
        }
    }
    __syncthreads();
    if (t == 0) {
        float s = 0.0f;
        #pragma unroll
        for (int k = 0; k < 64; ++k) s += qf_s[k];
        ws[WQBAR + b * 49 + l] = s * (1.0f / 64.0f);
    }
}

// K2: block 0 = stats (pc-row-means, sumq); blocks 1..128 = transpose+bf16 MLP weights
__global__ __launch_bounds__(1024) void k_prep(
    const float* __restrict__ pc_w, const float* __restrict__ pc_b,
    const float* __restrict__ pm_w, const float* __restrict__ qm_w,
    float* __restrict__ ws)
{
    int t = threadIdx.x;
    if (blockIdx.x == 0) {
        float s = 0.0f;
        for (int r = 0; r < 64; ++r) s += pc_w[r * 1024 + t];
        ws[WPCBW + t] = s * (1.0f / 64.0f);
        if (t == 0) {
            float sb = 0.0f;
            for (int r = 0; r < 64; ++r) sb += pc_b[r];
            ws[WPCBB] = sb * (1.0f / 64.0f);
        }
        if (t < 4) {
            float sq = 0.0f;
            for (int l = 0; l < 49; ++l) sq += ws[WQBAR + t * 49 + l];
            ws[WSUMQ + t] = sq;
        }
    } else {
        int idx = (blockIdx.x - 1) * 1024 + t;  // < 131072
        int r = (idx & 65535) >> 10, c = idx & 1023;
        float w = (idx < 65536) ? pm_w[c * 64 + r] : qm_w[c * 64 + r];
        unsigned short* dst = (unsigned short*)(ws + (idx < 65536 ? WPMBF : WQMBF));
        dst[idx & 65535] = bf16_rne(w);
    }
}

// K3: per-prop, register-resident x. Each thread owns 12(+1) float4 of the prop,
// captured during the LDS staging loads -> x fetched from HBM exactly once.
__global__ __launch_bounds__(1024) void k_prop(
    const float* __restrict__ x, const float* __restrict__ xq,
    const float* __restrict__ pc_w, const float* __restrict__ pc_b,
    const float* __restrict__ pm_b, const float* __restrict__ qm_b,
    const float* __restrict__ ws,
    float* __restrict__ fprops, float* __restrict__ fquery, float* __restrict__ patt_out)
{
    __shared__ float xs[12544];       // [256][49] one channel-chunk (50 KB)
    __shared__ float y_s[1024];       // y; reused as p_att
    __shared__ float pcb_s[1024];     // pc-row-means; reused as q_att
    __shared__ float qbar_s[49];
    __shared__ float pbar_part[4][49];
    __shared__ float pbar_s[49];
    __shared__ float prel_s[64];
    __shared__ float qrel_s[64];

    const int t = threadIdx.x, wave = t >> 6, lane = t & 63;
    const int p = blockIdx.x, b = p >> 8;

    if (t < 49) qbar_s[t] = ws[WQBAR + b * 49 + t];
    pcb_s[t] = ws[WPCBW + t];
    const float sumqbar = ws[WSUMQ + b];
    const float pcbarb  = ws[WPCBB];

    const float4* xp4 = (const float4*)(x + (size_t)p * 50176);
    float4* xs4 = (float4*)xs;
    float4 ra[12];                    // 12 float4 per thread (48 VGPR)
    float4 re[4];                     // extra slice, only threads t<64
    float pbar_acc = 0.0f;

    #pragma unroll
    for (int ch = 0; ch < 4; ++ch) {
        __syncthreads();              // xs free of prev readers (iter0: covers init)
        const float4* src = xp4 + ch * 3136;
        float4 v0 = src[t], v1 = src[t + 1024], v2 = src[t + 2048];
        xs4[t] = v0; xs4[t + 1024] = v1; xs4[t + 2048] = v2;
        ra[ch * 3 + 0] = v0; ra[ch * 3 + 1] = v1; ra[ch * 3 + 2] = v2;
        if (t < 64) { float4 v3 = src[t + 3072]; xs4[t + 3072] = v3; re[ch] = v3; }
        __syncthreads();
        if (wave < 4) {
            int c = wave * 64 + lane;
            const float* row = xs + c * 49;
            float acc = 0.0f;
            #pragma unroll
            for (int l = 0; l < 49; ++l) acc += row[l] * qbar_s[l];
            y_s[ch * 256 + c] = acc;
        } else if (wave < 8 && lane < 49) {
            int cw = (wave - 4) * 64;
            const float* base = xs + cw * 49 + lane;
            const float* pw = pcb_s + ch * 256 + cw;
            float a = 0.0f;
            #pragma unroll
            for (int c = 0; c < 64; ++c) a += pw[c] * base[c * 49];
            pbar_acc += a;
        }
    }
    if (wave >= 4 && wave < 8 && lane < 49) pbar_part[wave - 4][lane] = pbar_acc;
    __syncthreads();

    // p_rel[r] = pc_w[r,:].y + pc_b[r]*sumqbar ; 16 waves x 4 rows
    #pragma unroll
    for (int i2 = 0; i2 < 4; ++i2) {
        int r = wave * 4 + i2;
        const float* wr = pc_w + r * 1024;
        float part = 0.0f;
        #pragma unroll
        for (int k = 0; k < 16; ++k) part += wr[k * 64 + lane] * y_s[k * 64 + lane];
        #pragma unroll
        for (int off = 32; off; off >>= 1) part += __shfl_down(part, off, 64);
        if (lane == 0) prel_s[r] = part + pc_b[r] * sumqbar;
    }
    if (t < 49)
        pbar_s[t] = pbar_part[0][t] + pbar_part[1][t] + pbar_part[2][t] + pbar_part[3][t] + pcbarb;
    __syncthreads();
    if (t < 64) {
        const float* qfr = ws + WQF + (b * 3136 + t * 49);
        float a = 0.0f;
        #pragma unroll
        for (int l = 0; l < 49; ++l) a += pbar_s[l] * qfr[l];
        qrel_s[t] = a;
    }
    __syncthreads();

    // MLPs, bf16 weights: t<512 -> p_att pair (2t,2t+1), t>=512 -> q_att pair
    {
        int col2 = t & 511;
        const unsigned* wbf = (const unsigned*)(ws + (t < 512 ? WPMBF : WQMBF));
        const float* rel = (t < 512) ? prel_s : qrel_s;
        float a0 = 0.0f, a1 = 0.0f;
        #pragma unroll
        for (int r = 0; r < 64; ++r) {
            unsigned w2 = wbf[r * 512 + col2];
            float w0 = __uint_as_float(w2 << 16);
            float w1 = __uint_as_float(w2 & 0xFFFF0000u);
            float rv = rel[r];
            a0 += w0 * rv; a1 += w1 * rv;
        }
        const float* bias = (t < 512) ? pm_b : qm_b;
        float o0 = sigmoidf(a0 + bias[2 * col2]);
        float o1 = sigmoidf(a1 + bias[2 * col2 + 1]);
        if (t < 512) {
            y_s[2 * col2] = o0; y_s[2 * col2 + 1] = o1;
            float2 po; po.x = o0; po.y = o1;
            ((float2*)patt_out)[p * 512 + col2] = po;
        } else {
            pcb_s[2 * col2] = o0; pcb_s[2 * col2 + 1] = o1;
        }
    }
    __syncthreads();

    // f_props from registers (no global re-read); channel via exact magic-div by 49
    float4* fp4 = (float4*)(fprops + (size_t)p * 50176);
    #pragma unroll
    for (int ch = 0; ch < 4; ++ch) {
        #pragma unroll
        for (int j = 0; j < 3; ++j) {
            int g = ch * 3136 + j * 1024 + t;
            float4 v = ra[ch * 3 + j];
            unsigned e = 4u * (unsigned)g;
            unsigned c0 = (e * 85599u) >> 22;       // exact floor(e/49) for e < 89240
            unsigned m = e - 49u * c0;
            v.x *= y_s[c0];
            v.y *= y_s[c0 + (m >= 48u)];
            v.z *= y_s[c0 + (m >= 47u)];
            v.w *= y_s[c0 + (m >= 46u)];
            fp4[g] = v;
        }
    }
    if (t < 64) {
        #pragma unroll
        for (int ch = 0; ch < 4; ++ch) {
            int g = ch * 3136 + 3072 + t;
            float4 v = re[ch];
            unsigned e = 4u * (unsigned)g;
            unsigned c0 = (e * 85599u) >> 22;
            unsigned m = e - 49u * c0;
            v.x *= y_s[c0];
            v.y *= y_s[c0 + (m >= 48u)];
            v.z *= y_s[c0 + (m >= 47u)];
            v.w *= y_s[c0 + (m >= 46u)];
            fp4[g] = v;
        }
    }
    // f_query = x_query[b] * q_att (reads L2/L3-resident 16 MB)
    const float4* xq4 = (const float4*)(xq + ((size_t)b << 16));
    float4* fq4 = (float4*)(fquery + ((size_t)p << 16));
    #pragma unroll
    for (int i3 = 0; i3 < 16; ++i3) {
        int k = i3 * 1024 + t;
        float att = pcb_s[k >> 4];
        float4 v = xq4[k];
        v.x *= att; v.y *= att; v.z *= att; v.w *= att;
        fq4[k] = v;
    }
}

extern "C" void kernel_launch(void* const* d_in, const int* in_sizes, int n_in,
                              void* d_out, int out_size, void* d_ws, size_t ws_size,
                              hipStream_t stream) {
    const float* x_props = (const float*)d_in[0];
    const float* x_query = (const float*)d_in[1];
    const float* pc_w    = (const float*)d_in[2];
    const float* pc_b    = (const float*)d_in[3];
    const float* qc_w    = (const float*)d_in[4];
    const float* qc_b    = (const float*)d_in[5];
    const float* pm_w    = (const float*)d_in[6];
    const float* pm_b    = (const float*)d_in[7];
    const float* qm_w    = (const float*)d_in[8];
    const float* qm_b    = (const float*)d_in[9];
    float* out = (float*)d_out;
    float* ws  = (float*)d_ws;

    k_qprep<<<196, 1024, 0, stream>>>(x_query, qc_w, qc_b, ws);
    k_prep<<<129, 1024, 0, stream>>>(pc_w, pc_b, pm_w, qm_w, ws);
    k_prop<<<1024, 1024, 0, stream>>>(x_props, x_query, pc_w, pc_b, pm_b, qm_b, ws,
                                      out + OUT_FP, out + OUT_FQ, out + OUT_PA);
}